// Round 1
// baseline (112.945 us; speedup 1.0000x reference)
//
#include <hip/hip_runtime.h>
#include <stdint.h>

// Problem constants
#define B_N   32768
#define D_IN  35
#define H1N   256
#define H2N   256
#define NJ    12
#define NQ    7
#define NO    5
#define QO    35
#define QO_PAD 48
#define TILE  32
#define MAXTILES 1040   // ceil(32768/32) + 12 = 1036 max tiles

typedef __bf16  v8bf  __attribute__((ext_vector_type(8)));
typedef float   f32x4 __attribute__((ext_vector_type(4)));

__device__ __forceinline__ unsigned short f2bf(float f) {
    unsigned int u = __builtin_bit_cast(unsigned int, f);
    u += 0x7FFFu + ((u >> 16) & 1u);   // round-to-nearest-even
    return (unsigned short)(u >> 16);
}

// ---------------------------------------------------------------------------
// Kernel 1: combine shared+expert weights into bf16 arrays (ones-column folded
// into f32 biases) and count samples per expert.
// w1c: [12][256][64]  (cols 35..63 zero)   bf16
// w2c: [12][256][256]                       bf16
// vc : [12][48][256]  (rows 35..47 zero)    bf16
// ---------------------------------------------------------------------------
__global__ void k_prep(const int* __restrict__ ids,
                       const float* __restrict__ W1_w, const float* __restrict__ W1_b,
                       const float* __restrict__ W2_w, const float* __restrict__ W2_b,
                       const float* __restrict__ W1a_w, const float* __restrict__ W1a_b,
                       const float* __restrict__ W2a_w, const float* __restrict__ W2a_b,
                       const float* __restrict__ V_w,  const float* __restrict__ V_b,
                       const float* __restrict__ Va_w, const float* __restrict__ Va_b,
                       unsigned short* __restrict__ w1c, unsigned short* __restrict__ w2c,
                       unsigned short* __restrict__ vc,
                       float* __restrict__ bias1, float* __restrict__ bias2,
                       float* __restrict__ biasv, int* __restrict__ counts)
{
    const int tid = blockIdx.x * blockDim.x + threadIdx.x;
    const int nth = gridDim.x * blockDim.x;

    // w1c [j][h][k<64]
    for (int i = tid; i < NJ * H1N * 64; i += nth) {
        int k = i & 63, h = (i >> 6) & 255, j = i >> 14;
        float v = 0.f;
        if (k < D_IN) v = W1_w[h * 36 + k] + W1a_w[((j << 8) + h) * 36 + k];
        w1c[i] = f2bf(v);
    }
    // w2c [j][h][k<256]
    for (int i = tid; i < NJ * H2N * 256; i += nth) {
        int k = i & 255, h = (i >> 8) & 255, j = i >> 16;
        float v = W2_w[h * 257 + k] + W2a_w[((j << 8) + h) * 257 + k];
        w2c[i] = f2bf(v);
    }
    // vc [j][qo<48][k<256]
    for (int i = tid; i < NJ * QO_PAD * 256; i += nth) {
        int k = i & 255, qo = (i >> 8) % QO_PAD, j = i / (QO_PAD * 256);
        float v = 0.f;
        if (qo < QO) v = V_w[qo * 257 + k] + Va_w[(j * QO + qo) * 257 + k];
        vc[i] = f2bf(v);
    }
    // biases (fold ones-column weight)
    for (int i = tid; i < NJ * H1N; i += nth) {
        int h = i & 255, j = i >> 8;
        bias1[i] = W1_w[h * 36 + 35] + W1a_w[((j << 8) + h) * 36 + 35] + W1_b[h] + W1a_b[i];
        bias2[i] = W2_w[h * 257 + 256] + W2a_w[((j << 8) + h) * 257 + 256] + W2_b[h] + W2a_b[i];
    }
    for (int i = tid; i < NJ * QO_PAD; i += nth) {
        int qo = i % QO_PAD, j = i / QO_PAD;
        float v = 0.f;
        if (qo < QO) v = V_w[qo * 257 + 256] + Va_w[(j * QO + qo) * 257 + 256]
                       + V_b[qo] + Va_b[j * QO + qo];
        biasv[i] = v;
    }
    // per-block LDS histogram -> global counts
    __shared__ int lh[NJ];
    if (threadIdx.x < NJ) lh[threadIdx.x] = 0;
    __syncthreads();
    for (int i = tid; i < B_N; i += nth) atomicAdd(&lh[ids[i]], 1);
    __syncthreads();
    if (threadIdx.x < NJ && lh[threadIdx.x]) atomicAdd(&counts[threadIdx.x], lh[threadIdx.x]);
}

// ---------------------------------------------------------------------------
// Kernel 2: exclusive scan of counts -> cursors, build tile table.
// ---------------------------------------------------------------------------
__global__ void k_scan(const int* __restrict__ counts, int* __restrict__ cursor,
                       int* __restrict__ ntiles, int* __restrict__ tileExpert,
                       int* __restrict__ tileStart, int* __restrict__ tileLen)
{
    if (threadIdx.x == 0 && blockIdx.x == 0) {
        int off = 0, nt = 0;
        for (int j = 0; j < NJ; ++j) {
            int c = counts[j];
            cursor[j] = off;
            for (int t = 0; t < c; t += TILE) {
                tileExpert[nt] = j;
                tileStart[nt]  = off + t;
                tileLen[nt]    = (c - t) < TILE ? (c - t) : TILE;
                ++nt;
            }
            off += c;
        }
        ntiles[0] = nt;
    }
}

// ---------------------------------------------------------------------------
// Kernel 3: scatter sample indices into expert-sorted permutation.
// ---------------------------------------------------------------------------
__global__ void k_scatter(const int* __restrict__ ids, int* __restrict__ cursor,
                          int* __restrict__ perm)
{
    __shared__ int lh[NJ], lbase[NJ];
    const int b = blockIdx.x * blockDim.x + threadIdx.x;
    if (threadIdx.x < NJ) lh[threadIdx.x] = 0;
    __syncthreads();
    int id = 0, rank = 0;
    if (b < B_N) { id = ids[b]; rank = atomicAdd(&lh[id], 1); }
    __syncthreads();
    if (threadIdx.x < NJ)
        lbase[threadIdx.x] = lh[threadIdx.x] ? atomicAdd(&cursor[threadIdx.x], lh[threadIdx.x]) : 0;
    __syncthreads();
    if (b < B_N) perm[lbase[id] + rank] = b;
}

// ---------------------------------------------------------------------------
// Kernel 4: fused MLP for one (expert, 32-sample) tile.
// 4 waves: wave = (n-half << 1) | m-half ... mapped as mt = wave&1, nb = (wave>>1)*8.
// MFMA fragment layout (gfx950 16x16x32 bf16, verified per guide):
//   A: lane holds A[lane&15][(lane>>4)*8 + e]   (8 contiguous k -> one b128)
//   B: lane holds B[(lane>>4)*8 + e][lane&15]   (row-major [n][k] -> one b128)
//   D: col = lane&15, row = (lane>>4)*4 + reg
// ---------------------------------------------------------------------------
__global__ __launch_bounds__(256) void k_main(
    const float* __restrict__ x, float* __restrict__ out,
    const int* __restrict__ perm, const int* __restrict__ ntiles,
    const int* __restrict__ tileExpert, const int* __restrict__ tileStart,
    const int* __restrict__ tileLen,
    const unsigned short* __restrict__ w1c, const unsigned short* __restrict__ w2c,
    const unsigned short* __restrict__ vc,
    const float* __restrict__ bias1, const float* __restrict__ bias2,
    const float* __restrict__ biasv)
{
    __shared__ int s_rows[TILE];
    __shared__ __align__(16) unsigned short s_xb[TILE][72];   // bf16, cols>=35 zero
    __shared__ __align__(16) unsigned short s_z1[TILE][264];  // bf16, k=0..255 used
    __shared__ __align__(16) unsigned short s_z2[TILE][264];
    __shared__ float s_logits[TILE][QO_PAD];

    const int bid = blockIdx.x;
    if (bid >= ntiles[0]) return;
    const int tid   = threadIdx.x;
    const int j     = tileExpert[bid];
    const int start = tileStart[bid];
    const int m     = tileLen[bid];

    if (tid < TILE) s_rows[tid] = (tid < m) ? perm[start + tid] : -1;
    __syncthreads();

    // stage x tile as bf16 (zero-padded)
    for (int i = tid; i < TILE * 72; i += 256) {
        int s = i / 72, k = i % 72;
        float v = 0.f;
        int r = s_rows[s];
        if (r >= 0 && k < D_IN) v = x[r * D_IN + k];
        s_xb[s][k] = f2bf(v);
    }
    __syncthreads();

    const int lane = tid & 63;
    const int wave = tid >> 6;
    const int l16  = lane & 15;
    const int lk   = lane >> 4;        // 0..3 (k-group)
    const int mt   = wave & 1;         // m-tile (16 samples)
    const int nb   = (wave >> 1) * 8;  // base n-tile (8 tiles of 16)

    const f32x4 vzero = {0.f, 0.f, 0.f, 0.f};

    // ---------------- layer 1: z1 = relu(x @ W1c^T + bias1) ----------------
    {
        f32x4 acc[8];
#pragma unroll
        for (int n = 0; n < 8; ++n) acc[n] = vzero;
#pragma unroll
        for (int ks = 0; ks < 2; ++ks) {
            v8bf a = *(const v8bf*)&s_xb[mt * 16 + l16][ks * 32 + lk * 8];
#pragma unroll
            for (int n = 0; n < 8; ++n) {
                int h = (nb + n) * 16 + l16;
                v8bf b = *(const v8bf*)&w1c[(((size_t)j * 256 + h) << 6) + ks * 32 + lk * 8];
                acc[n] = __builtin_amdgcn_mfma_f32_16x16x32_bf16(a, b, acc[n], 0, 0, 0);
            }
        }
#pragma unroll
        for (int n = 0; n < 8; ++n) {
            int h = (nb + n) * 16 + l16;
            float bz = bias1[j * 256 + h];
#pragma unroll
            for (int r = 0; r < 4; ++r) {
                float v = acc[n][r] + bz;
                s_z1[mt * 16 + lk * 4 + r][h] = f2bf(v > 0.f ? v : 0.f);
            }
        }
    }
    __syncthreads();

    // ---------------- layer 2: z2 = relu(z1 @ W2c^T + bias2) ---------------
    {
        f32x4 acc[8];
#pragma unroll
        for (int n = 0; n < 8; ++n) acc[n] = vzero;
#pragma unroll
        for (int ks = 0; ks < 8; ++ks) {
            v8bf a = *(const v8bf*)&s_z1[mt * 16 + l16][ks * 32 + lk * 8];
#pragma unroll
            for (int n = 0; n < 8; ++n) {
                int h = (nb + n) * 16 + l16;
                v8bf b = *(const v8bf*)&w2c[(((size_t)j * 256 + h) << 8) + ks * 32 + lk * 8];
                acc[n] = __builtin_amdgcn_mfma_f32_16x16x32_bf16(a, b, acc[n], 0, 0, 0);
            }
        }
#pragma unroll
        for (int n = 0; n < 8; ++n) {
            int h = (nb + n) * 16 + l16;
            float bz = bias2[j * 256 + h];
#pragma unroll
            for (int r = 0; r < 4; ++r) {
                float v = acc[n][r] + bz;
                s_z2[mt * 16 + lk * 4 + r][h] = f2bf(v > 0.f ? v : 0.f);
            }
        }
    }
    __syncthreads();

    // ---------------- heads: logits = z2 @ Vc^T + biasv --------------------
    if (wave < 2) {
        f32x4 acc[3];
#pragma unroll
        for (int n = 0; n < 3; ++n) acc[n] = vzero;
#pragma unroll
        for (int ks = 0; ks < 8; ++ks) {
            v8bf a = *(const v8bf*)&s_z2[wave * 16 + l16][ks * 32 + lk * 8];
#pragma unroll
            for (int n = 0; n < 3; ++n) {
                int qo = n * 16 + l16;
                v8bf b = *(const v8bf*)&vc[(((size_t)j * QO_PAD + qo) << 8) + ks * 32 + lk * 8];
                acc[n] = __builtin_amdgcn_mfma_f32_16x16x32_bf16(a, b, acc[n], 0, 0, 0);
            }
        }
#pragma unroll
        for (int n = 0; n < 3; ++n) {
            int qo = n * 16 + l16;
            float bz = biasv[j * QO_PAD + qo];
#pragma unroll
            for (int r = 0; r < 4; ++r)
                s_logits[wave * 16 + lk * 4 + r][qo] = acc[n][r] + bz;
        }
    }
    __syncthreads();

    // ---------------- softmax over O=5 within each (sample, q) -------------
    if (tid < TILE * NQ) {
        int s = tid / NQ, q = tid % NQ;
        if (s < m) {
            float l[NO], mx = -1e30f;
#pragma unroll
            for (int o = 0; o < NO; ++o) {
                l[o] = s_logits[s][q * NO + o];
                mx = l[o] > mx ? l[o] : mx;
            }
            float sum = 0.f, e[NO];
#pragma unroll
            for (int o = 0; o < NO; ++o) { e[o] = __expf(l[o] - mx); sum += e[o]; }
            float inv = 1.f / sum;
            int r = s_rows[s];
            float* op = out + (size_t)r * QO + q * NO;
#pragma unroll
            for (int o = 0; o < NO; ++o) op[o] = e[o] * inv;
        }
    }
}

// ---------------------------------------------------------------------------
extern "C" void kernel_launch(void* const* d_in, const int* in_sizes, int n_in,
                              void* d_out, int out_size, void* d_ws, size_t ws_size,
                              hipStream_t stream)
{
    const float* x     = (const float*)d_in[0];
    const int*   ids   = (const int*)d_in[1];
    const float* W1_w  = (const float*)d_in[2];
    const float* W1_b  = (const float*)d_in[3];
    const float* W2_w  = (const float*)d_in[4];
    const float* W2_b  = (const float*)d_in[5];
    const float* W1a_w = (const float*)d_in[6];
    const float* W1a_b = (const float*)d_in[7];
    const float* W2a_w = (const float*)d_in[8];
    const float* W2a_b = (const float*)d_in[9];
    const float* V_w   = (const float*)d_in[10];
    const float* V_b   = (const float*)d_in[11];
    const float* Va_w  = (const float*)d_in[12];
    const float* Va_b  = (const float*)d_in[13];
    float* out = (float*)d_out;

    char* ws = (char*)d_ws;
    size_t off = 0;
    auto take = [&](size_t nbytes) -> void* {
        void* p = ws + off;
        off = (off + nbytes + 255) & ~(size_t)255;
        return p;
    };
    unsigned short* w1c   = (unsigned short*)take((size_t)NJ * H1N * 64 * 2);
    unsigned short* w2c   = (unsigned short*)take((size_t)NJ * H2N * 256 * 2);
    unsigned short* vc    = (unsigned short*)take((size_t)NJ * QO_PAD * 256 * 2);
    float* bias1          = (float*)take((size_t)NJ * H1N * 4);
    float* bias2          = (float*)take((size_t)NJ * H2N * 4);
    float* biasv          = (float*)take((size_t)NJ * QO_PAD * 4);
    int* counts           = (int*)take(NJ * 4);
    int* cursor           = (int*)take(NJ * 4);
    int* ntiles           = (int*)take(4);
    int* tileExpert       = (int*)take(MAXTILES * 4);
    int* tileStart        = (int*)take(MAXTILES * 4);
    int* tileLen          = (int*)take(MAXTILES * 4);
    int* perm             = (int*)take((size_t)B_N * 4);

    hipMemsetAsync(counts, 0, NJ * sizeof(int), stream);

    k_prep<<<512, 256, 0, stream>>>(ids, W1_w, W1_b, W2_w, W2_b, W1a_w, W1a_b,
                                    W2a_w, W2a_b, V_w, V_b, Va_w, Va_b,
                                    w1c, w2c, vc, bias1, bias2, biasv, counts);
    k_scan<<<1, 64, 0, stream>>>(counts, cursor, ntiles, tileExpert, tileStart, tileLen);
    k_scatter<<<(B_N + 255) / 256, 256, 0, stream>>>(ids, cursor, perm);
    k_main<<<MAXTILES, 256, 0, stream>>>(x, out, perm, ntiles, tileExpert, tileStart,
                                         tileLen, w1c, w2c, vc, bias1, bias2, biasv);
}

// Round 2
// 107.315 us; speedup vs baseline: 1.0525x; 1.0525x over previous
//
#include <hip/hip_runtime.h>
#include <stdint.h>

// Problem constants
#define B_N   32768
#define D_IN  35
#define NJ    12
#define NQ    7
#define NO    5
#define QO    35
#define SPW   16                      // samples per wave
#define MAXSLOTS (B_N + NJ*SPW)       // padded permutation slots (32960)
#define MAXT16   (MAXSLOTS/16)        // 2060 16-sample tiles max

typedef __bf16  v8bf  __attribute__((ext_vector_type(8)));
typedef float   f32x4 __attribute__((ext_vector_type(4)));

__device__ __forceinline__ unsigned short f2bf(float f) {
    unsigned int u = __builtin_bit_cast(unsigned int, f);
    u += 0x7FFFu + ((u >> 16) & 1u);   // round-to-nearest-even
    return (unsigned short)(u >> 16);
}
__device__ __forceinline__ unsigned int pack2(float a, float b) {
    return (unsigned int)f2bf(a) | ((unsigned int)f2bf(b) << 16);
}

// ---------------------------------------------------------------------------
// Kernel 1: combine shared+expert weights into bf16 (ones-col folded into f32
// biases) + per-expert histogram.  Vectorized: 1 thread -> 4 bf16 (ushort4).
// w1c: [12][256][64]  (k>=35 zero)    w2c: [12][256][256]    vc: [12][48][256]
// ---------------------------------------------------------------------------
__global__ void k_prep(const int* __restrict__ ids,
                       const float* __restrict__ W1_w, const float* __restrict__ W1_b,
                       const float* __restrict__ W2_w, const float* __restrict__ W2_b,
                       const float* __restrict__ W1a_w, const float* __restrict__ W1a_b,
                       const float* __restrict__ W2a_w, const float* __restrict__ W2a_b,
                       const float* __restrict__ V_w,  const float* __restrict__ V_b,
                       const float* __restrict__ Va_w, const float* __restrict__ Va_b,
                       unsigned short* __restrict__ w1c, unsigned short* __restrict__ w2c,
                       unsigned short* __restrict__ vc,
                       float* __restrict__ bias1, float* __restrict__ bias2,
                       float* __restrict__ biasv, int* __restrict__ counts)
{
    const int tid = blockIdx.x * blockDim.x + threadIdx.x;
    const int nth = gridDim.x * blockDim.x;

    // w2c: 12*256*64 quads
    for (int q = tid; q < NJ * 256 * 64; q += nth) {
        int k4 = (q & 63) << 2, h = (q >> 6) & 255, jj = q >> 14;
        const float* a = &W2_w[h * 257 + k4];
        const float* b = &W2a_w[(jj * 256 + h) * 257 + k4];
        ushort4 o;
        o.x = f2bf(a[0] + b[0]); o.y = f2bf(a[1] + b[1]);
        o.z = f2bf(a[2] + b[2]); o.w = f2bf(a[3] + b[3]);
        *(ushort4*)&w2c[(size_t)q << 2] = o;
    }
    // w1c: 12*256*16 quads (k padded to 64)
    for (int q = tid; q < NJ * 256 * 16; q += nth) {
        int k4 = (q & 15) << 2, h = (q >> 4) & 255, jj = q >> 12;
        ushort4 o;
        float v[4];
#pragma unroll
        for (int e = 0; e < 4; ++e) {
            int k = k4 + e;
            v[e] = (k < D_IN) ? (W1_w[h * 36 + k] + W1a_w[(jj * 256 + h) * 36 + k]) : 0.f;
        }
        o.x = f2bf(v[0]); o.y = f2bf(v[1]); o.z = f2bf(v[2]); o.w = f2bf(v[3]);
        *(ushort4*)&w1c[(size_t)q << 2] = o;
    }
    // vc: 12*48*64 quads
    for (int q = tid; q < NJ * 48 * 64; q += nth) {
        int k4 = (q & 63) << 2, qo = (q >> 6) % 48, jj = q / (48 * 64);
        ushort4 o;
        if (qo < QO) {
            const float* a = &V_w[qo * 257 + k4];
            const float* b = &Va_w[(jj * QO + qo) * 257 + k4];
            o.x = f2bf(a[0] + b[0]); o.y = f2bf(a[1] + b[1]);
            o.z = f2bf(a[2] + b[2]); o.w = f2bf(a[3] + b[3]);
        } else {
            o.x = o.y = o.z = o.w = 0;
        }
        *(ushort4*)&vc[(size_t)q << 2] = o;
    }
    // biases (fold ones-column)
    for (int i = tid; i < NJ * 256; i += nth) {
        int h = i & 255, jj = i >> 8;
        bias1[i] = W1_w[h * 36 + 35] + W1a_w[(jj * 256 + h) * 36 + 35] + W1_b[h] + W1a_b[i];
        bias2[i] = W2_w[h * 257 + 256] + W2a_w[(jj * 256 + h) * 257 + 256] + W2_b[h] + W2a_b[i];
    }
    for (int i = tid; i < NJ * 48; i += nth) {
        int qo = i % 48, jj = i / 48;
        float v = 0.f;
        if (qo < QO) v = V_w[qo * 257 + 256] + Va_w[(jj * QO + qo) * 257 + 256]
                       + V_b[qo] + Va_b[jj * QO + qo];
        biasv[i] = v;
    }
    // histogram
    __shared__ int lh[NJ];
    if (threadIdx.x < NJ) lh[threadIdx.x] = 0;
    __syncthreads();
    for (int i = tid; i < B_N; i += nth) atomicAdd(&lh[ids[i]], 1);
    __syncthreads();
    if (threadIdx.x < NJ && lh[threadIdx.x]) atomicAdd(&counts[threadIdx.x], lh[threadIdx.x]);
}

// ---------------------------------------------------------------------------
// Kernel 2: padded prefix (each expert padded to mult of 16) + tile table.
// ---------------------------------------------------------------------------
__global__ void k_scan(const int* __restrict__ counts, int* __restrict__ cursor,
                       int* __restrict__ ntiles16, int* __restrict__ tileExpert)
{
    __shared__ int tb[NJ + 1];
    if (threadIdx.x == 0) {
        int off = 0, t = 0;
        for (int j = 0; j < NJ; ++j) {
            cursor[j] = off;               // scatter base (padded offset)
            tb[j] = t;
            int nt = (counts[j] + SPW - 1) / SPW;
            t += nt;
            off += nt * SPW;
        }
        tb[NJ] = t;
        ntiles16[0] = t;
    }
    __syncthreads();
    int ntot = tb[NJ];
    for (int tt = threadIdx.x; tt < ntot; tt += blockDim.x) {
        int j = 0;
        while (tb[j + 1] <= tt) ++j;
        tileExpert[tt] = j;
    }
}

// ---------------------------------------------------------------------------
// Kernel 3: scatter sample indices (perm pre-memset to -1; padded slots stay -1)
// ---------------------------------------------------------------------------
__global__ void k_scatter(const int* __restrict__ ids, int* __restrict__ cursor,
                          int* __restrict__ perm)
{
    __shared__ int lh[NJ], lbase[NJ];
    const int b = blockIdx.x * blockDim.x + threadIdx.x;
    if (threadIdx.x < NJ) lh[threadIdx.x] = 0;
    __syncthreads();
    int id = 0, rank = 0;
    if (b < B_N) { id = ids[b]; rank = atomicAdd(&lh[id], 1); }
    __syncthreads();
    if (threadIdx.x < NJ)
        lbase[threadIdx.x] = lh[threadIdx.x] ? atomicAdd(&cursor[threadIdx.x], lh[threadIdx.x]) : 0;
    __syncthreads();
    if (b < B_N) perm[lbase[id] + rank] = b;
}

// ---------------------------------------------------------------------------
// Kernel 4: fully wave-independent fused MLP. One wave = 16 samples, one
// expert. NO __syncthreads anywhere. Weights are the MFMA A-operand (rows),
// samples are the B-operand columns; activations live in a per-wave LDS strip.
// MFMA 16x16x32 bf16 layouts:
//   A: lane holds A[lane&15][(lane>>4)*8+e]
//   B: lane holds B[(lane>>4)*8+e][lane&15]
//   D: col=lane&15, row=(lane>>4)*4+r
// ---------------------------------------------------------------------------
__global__ __launch_bounds__(256) void k_main(
    const float* __restrict__ x, float* __restrict__ out,
    const int* __restrict__ perm, const int* __restrict__ ntiles16,
    const int* __restrict__ tileExpert,
    const unsigned short* __restrict__ w1c, const unsigned short* __restrict__ w2c,
    const unsigned short* __restrict__ vc,
    const float* __restrict__ bias1, const float* __restrict__ bias2,
    const float* __restrict__ biasv)
{
    __shared__ __align__(16) unsigned short s_xb[4][SPW][72];   // bf16 input, k>=35 zero
    __shared__ __align__(16) unsigned short s_z[4][SPW][264];   // z1 then z2 (bf16)
    __shared__ __align__(16) float          s_lg[4][SPW][40];   // logits
    __shared__ int                          s_rows[4][SPW];

    const int wave = threadIdx.x >> 6;
    const int lane = threadIdx.x & 63;
    const int wid  = blockIdx.x * 4 + wave;
    if (wid >= ntiles16[0]) return;            // safe: no barriers in this kernel

    const int j   = tileExpert[wid];
    const int l16 = lane & 15;
    const int lk  = lane >> 4;

    if (lane < SPW) s_rows[wave][lane] = perm[wid * SPW + lane];

    // ---- stage x tile (bf16, zero-padded to k<64) ----
    for (int i = lane; i < SPW * 36; i += 64)          // zero 16x72 shorts
        ((unsigned int*)&s_xb[wave][0][0])[i] = 0u;
    for (int i = lane; i < SPW * D_IN; i += 64) {
        int s = i / D_IN, k = i % D_IN;
        int r = s_rows[wave][s];
        float v = (r >= 0) ? x[r * D_IN + k] : 0.f;
        s_xb[wave][s][k] = f2bf(v);
    }

    // B1 fragments (same for all h-tiles): B[k][s] = xb[s][k]
    v8bf b1_0 = *(const v8bf*)&s_xb[wave][l16][lk * 8];
    v8bf b1_1 = *(const v8bf*)&s_xb[wave][l16][32 + lk * 8];

    const f32x4 vz = {0.f, 0.f, 0.f, 0.f};

    // ---- layer 1: z1[s][h] = relu(W1c[h]·xb[s] + bias1[h]) ----
    {
        const unsigned short* w1p = w1c + ((size_t)j << 14);
#pragma unroll 4
        for (int t = 0; t < 16; ++t) {
            v8bf a0 = *(const v8bf*)&w1p[(t * 16 + l16) * 64 + lk * 8];
            v8bf a1 = *(const v8bf*)&w1p[(t * 16 + l16) * 64 + 32 + lk * 8];
            f32x4 acc = vz;
            acc = __builtin_amdgcn_mfma_f32_16x16x32_bf16(a0, b1_0, acc, 0, 0, 0);
            acc = __builtin_amdgcn_mfma_f32_16x16x32_bf16(a1, b1_1, acc, 0, 0, 0);
            f32x4 bz = *(const f32x4*)&bias1[j * 256 + t * 16 + lk * 4];
            float v0 = acc[0] + bz[0], v1 = acc[1] + bz[1];
            float v2 = acc[2] + bz[2], v3 = acc[3] + bz[3];
            v0 = v0 > 0.f ? v0 : 0.f; v1 = v1 > 0.f ? v1 : 0.f;
            v2 = v2 > 0.f ? v2 : 0.f; v3 = v3 > 0.f ? v3 : 0.f;
            uint2 pk; pk.x = pack2(v0, v1); pk.y = pack2(v2, v3);
            // h = t*16 + lk*4 + r, col s = l16
            *(uint2*)&s_z[wave][l16][t * 16 + lk * 4] = pk;
        }
    }

    // ---- layer 2: z2[s][g] = relu(W2c[g]·z1[s] + bias2[g]) ----
    {
        f32x4 acc2[16];
#pragma unroll
        for (int gt = 0; gt < 16; ++gt) acc2[gt] = vz;
        const unsigned short* w2p = w2c + ((size_t)j << 16);
        for (int hc = 0; hc < 8; ++hc) {
            v8bf b2 = *(const v8bf*)&s_z[wave][l16][hc * 32 + lk * 8];
#pragma unroll
            for (int gt = 0; gt < 16; ++gt) {
                v8bf a = *(const v8bf*)&w2p[(gt * 16 + l16) * 256 + hc * 32 + lk * 8];
                acc2[gt] = __builtin_amdgcn_mfma_f32_16x16x32_bf16(a, b2, acc2[gt], 0, 0, 0);
            }
        }
#pragma unroll
        for (int gt = 0; gt < 16; ++gt) {
            f32x4 bz = *(const f32x4*)&bias2[j * 256 + gt * 16 + lk * 4];
            float v0 = acc2[gt][0] + bz[0], v1 = acc2[gt][1] + bz[1];
            float v2 = acc2[gt][2] + bz[2], v3 = acc2[gt][3] + bz[3];
            v0 = v0 > 0.f ? v0 : 0.f; v1 = v1 > 0.f ? v1 : 0.f;
            v2 = v2 > 0.f ? v2 : 0.f; v3 = v3 > 0.f ? v3 : 0.f;
            uint2 pk; pk.x = pack2(v0, v1); pk.y = pack2(v2, v3);
            *(uint2*)&s_z[wave][l16][gt * 16 + lk * 4] = pk;
        }
    }

    // ---- heads: logits[s][qo] = Vc[qo]·z2[s] + biasv[qo] ----
    {
        f32x4 accv[3];
#pragma unroll
        for (int n = 0; n < 3; ++n) accv[n] = vz;
        const unsigned short* vp = vc + (size_t)j * 48 * 256;
        for (int gc = 0; gc < 8; ++gc) {
            v8bf b3 = *(const v8bf*)&s_z[wave][l16][gc * 32 + lk * 8];
#pragma unroll
            for (int n = 0; n < 3; ++n) {
                v8bf a = *(const v8bf*)&vp[(n * 16 + l16) * 256 + gc * 32 + lk * 8];
                accv[n] = __builtin_amdgcn_mfma_f32_16x16x32_bf16(a, b3, accv[n], 0, 0, 0);
            }
        }
#pragma unroll
        for (int n = 0; n < 3; ++n) {
            int qb = n * 16 + lk * 4;                 // qo base
            if (qb < 36) {
                f32x4 bz = *(const f32x4*)&biasv[j * 48 + qb];
                f32x4 v;
                v[0] = accv[n][0] + bz[0]; v[1] = accv[n][1] + bz[1];
                v[2] = accv[n][2] + bz[2]; v[3] = accv[n][3] + bz[3];
                *(f32x4*)&s_lg[wave][l16][qb] = v;    // rows qb..qb+3, col s=l16
            }
        }
    }

    // ---- softmax over O=5 per (s,q), write out ----
    for (int p = lane; p < SPW * NQ; p += 64) {
        int s = p / NQ, q = p % NQ;
        int r = s_rows[wave][s];
        if (r >= 0) {
            float l[NO], mx = -1e30f;
#pragma unroll
            for (int o = 0; o < NO; ++o) {
                l[o] = s_lg[wave][s][q * NO + o];
                mx = l[o] > mx ? l[o] : mx;
            }
            float sum = 0.f, e[NO];
#pragma unroll
            for (int o = 0; o < NO; ++o) { e[o] = __expf(l[o] - mx); sum += e[o]; }
            float inv = 1.f / sum;
            float* op = out + (size_t)r * QO + q * NO;
#pragma unroll
            for (int o = 0; o < NO; ++o) op[o] = e[o] * inv;
        }
    }
}

// ---------------------------------------------------------------------------
extern "C" void kernel_launch(void* const* d_in, const int* in_sizes, int n_in,
                              void* d_out, int out_size, void* d_ws, size_t ws_size,
                              hipStream_t stream)
{
    const float* x     = (const float*)d_in[0];
    const int*   ids   = (const int*)d_in[1];
    const float* W1_w  = (const float*)d_in[2];
    const float* W1_b  = (const float*)d_in[3];
    const float* W2_w  = (const float*)d_in[4];
    const float* W2_b  = (const float*)d_in[5];
    const float* W1a_w = (const float*)d_in[6];
    const float* W1a_b = (const float*)d_in[7];
    const float* W2a_w = (const float*)d_in[8];
    const float* W2a_b = (const float*)d_in[9];
    const float* V_w   = (const float*)d_in[10];
    const float* V_b   = (const float*)d_in[11];
    const float* Va_w  = (const float*)d_in[12];
    const float* Va_b  = (const float*)d_in[13];
    float* out = (float*)d_out;

    char* ws = (char*)d_ws;
    size_t off = 0;
    auto take = [&](size_t nbytes) -> void* {
        void* p = ws + off;
        off = (off + nbytes + 255) & ~(size_t)255;
        return p;
    };
    unsigned short* w1c = (unsigned short*)take((size_t)NJ * 256 * 64 * 2);
    unsigned short* w2c = (unsigned short*)take((size_t)NJ * 256 * 256 * 2);
    unsigned short* vc  = (unsigned short*)take((size_t)NJ * 48 * 256 * 2);
    float* bias1        = (float*)take((size_t)NJ * 256 * 4);
    float* bias2        = (float*)take((size_t)NJ * 256 * 4);
    float* biasv        = (float*)take((size_t)NJ * 48 * 4);
    int* counts         = (int*)take(NJ * 4);
    int* cursor         = (int*)take(NJ * 4);
    int* ntiles16       = (int*)take(4);
    int* tileExpert     = (int*)take(MAXT16 * 4);
    int* perm           = (int*)take((size_t)MAXSLOTS * 4);

    hipMemsetAsync(counts, 0, NJ * sizeof(int), stream);
    hipMemsetAsync(perm, 0xFF, (size_t)MAXSLOTS * sizeof(int), stream);   // -1

    k_prep<<<768, 256, 0, stream>>>(ids, W1_w, W1_b, W2_w, W2_b, W1a_w, W1a_b,
                                    W2a_w, W2a_b, V_w, V_b, Va_w, Va_b,
                                    w1c, w2c, vc, bias1, bias2, biasv, counts);
    k_scan<<<1, 256, 0, stream>>>(counts, cursor, ntiles16, tileExpert);
    k_scatter<<<(B_N + 255) / 256, 256, 0, stream>>>(ids, cursor, perm);
    k_main<<<(MAXT16 + 3) / 4, 256, 0, stream>>>(x, out, perm, ntiles16, tileExpert,
                                                 w1c, w2c, vc, bias1, bias2, biasv);
}

// Round 3
// 55.423 us; speedup vs baseline: 2.0379x; 1.9363x over previous
//
#include <hip/hip_runtime.h>
#include <stdint.h>

// Problem constants
#define B_N   32768
#define D_IN  35
#define NJ    12
#define NQ    7
#define NO    5
#define QO    35
#define TILE  32                       // samples per block
#define MAXSLOTS (B_N + NJ*TILE)       // 33152 padded permutation slots
#define MAXT     (MAXSLOTS/TILE)       // 1036 tiles max

typedef __bf16  v8bf  __attribute__((ext_vector_type(8)));
typedef float   f32x4 __attribute__((ext_vector_type(4)));

__device__ __forceinline__ unsigned short f2bf(float f) {
    unsigned int u = __builtin_bit_cast(unsigned int, f);
    u += 0x7FFFu + ((u >> 16) & 1u);   // round-to-nearest-even
    return (unsigned short)(u >> 16);
}
__device__ __forceinline__ unsigned int pack2(float a, float b) {
    return (unsigned int)f2bf(a) | ((unsigned int)f2bf(b) << 16);
}

// ---------------------------------------------------------------------------
// Kernel 1: combine shared+expert weights into bf16 (ones-col folded into f32
// biases) + per-expert histogram.  Vectorized: 1 thread -> 4 bf16 (ushort4).
// w1c: [12][256][64] (k>=35 zero)   w2c: [12][256][256]   vc: [12][48][256]
// ---------------------------------------------------------------------------
__global__ void k_prep(const int* __restrict__ ids,
                       const float* __restrict__ W1_w, const float* __restrict__ W1_b,
                       const float* __restrict__ W2_w, const float* __restrict__ W2_b,
                       const float* __restrict__ W1a_w, const float* __restrict__ W1a_b,
                       const float* __restrict__ W2a_w, const float* __restrict__ W2a_b,
                       const float* __restrict__ V_w,  const float* __restrict__ V_b,
                       const float* __restrict__ Va_w, const float* __restrict__ Va_b,
                       unsigned short* __restrict__ w1c, unsigned short* __restrict__ w2c,
                       unsigned short* __restrict__ vc,
                       float* __restrict__ bias1, float* __restrict__ bias2,
                       float* __restrict__ biasv, int* __restrict__ counts)
{
    const int tid = blockIdx.x * blockDim.x + threadIdx.x;
    const int nth = gridDim.x * blockDim.x;

    // w2c: 12*256*64 quads
    for (int q = tid; q < NJ * 256 * 64; q += nth) {
        int k4 = (q & 63) << 2, h = (q >> 6) & 255, jj = q >> 14;
        const float* a = &W2_w[h * 257 + k4];
        const float* b = &W2a_w[(jj * 256 + h) * 257 + k4];
        ushort4 o;
        o.x = f2bf(a[0] + b[0]); o.y = f2bf(a[1] + b[1]);
        o.z = f2bf(a[2] + b[2]); o.w = f2bf(a[3] + b[3]);
        *(ushort4*)&w2c[(size_t)q << 2] = o;
    }
    // w1c: 12*256*16 quads (k padded to 64)
    for (int q = tid; q < NJ * 256 * 16; q += nth) {
        int k4 = (q & 15) << 2, h = (q >> 4) & 255, jj = q >> 12;
        ushort4 o;
        float v[4];
#pragma unroll
        for (int e = 0; e < 4; ++e) {
            int k = k4 + e;
            v[e] = (k < D_IN) ? (W1_w[h * 36 + k] + W1a_w[(jj * 256 + h) * 36 + k]) : 0.f;
        }
        o.x = f2bf(v[0]); o.y = f2bf(v[1]); o.z = f2bf(v[2]); o.w = f2bf(v[3]);
        *(ushort4*)&w1c[(size_t)q << 2] = o;
    }
    // vc: 12*48*64 quads
    for (int q = tid; q < NJ * 48 * 64; q += nth) {
        int k4 = (q & 63) << 2, qo = (q >> 6) % 48, jj = q / (48 * 64);
        ushort4 o;
        if (qo < QO) {
            const float* a = &V_w[qo * 257 + k4];
            const float* b = &Va_w[(jj * QO + qo) * 257 + k4];
            o.x = f2bf(a[0] + b[0]); o.y = f2bf(a[1] + b[1]);
            o.z = f2bf(a[2] + b[2]); o.w = f2bf(a[3] + b[3]);
        } else {
            o.x = o.y = o.z = o.w = 0;
        }
        *(ushort4*)&vc[(size_t)q << 2] = o;
    }
    // biases (fold ones-column)
    for (int i = tid; i < NJ * 256; i += nth) {
        int h = i & 255, jj = i >> 8;
        bias1[i] = W1_w[h * 36 + 35] + W1a_w[(jj * 256 + h) * 36 + 35] + W1_b[h] + W1a_b[i];
        bias2[i] = W2_w[h * 257 + 256] + W2a_w[(jj * 256 + h) * 257 + 256] + W2_b[h] + W2a_b[i];
    }
    for (int i = tid; i < NJ * 48; i += nth) {
        int qo = i % 48, jj = i / 48;
        float v = 0.f;
        if (qo < QO) v = V_w[qo * 257 + 256] + Va_w[(jj * QO + qo) * 257 + 256]
                       + V_b[qo] + Va_b[jj * QO + qo];
        biasv[i] = v;
    }
    // histogram
    __shared__ int lh[NJ];
    if (threadIdx.x < NJ) lh[threadIdx.x] = 0;
    __syncthreads();
    for (int i = tid; i < B_N; i += nth) atomicAdd(&lh[ids[i]], 1);
    __syncthreads();
    if (threadIdx.x < NJ && lh[threadIdx.x]) atomicAdd(&counts[threadIdx.x], lh[threadIdx.x]);
}

// ---------------------------------------------------------------------------
// Kernel 2: padded prefix (each expert padded to mult of TILE) + tile table.
// ---------------------------------------------------------------------------
__global__ void k_scan(const int* __restrict__ counts, int* __restrict__ cursor,
                       int* __restrict__ ntiles, int* __restrict__ tileExpert)
{
    __shared__ int tb[NJ + 1];
    if (threadIdx.x == 0) {
        int off = 0, t = 0;
        for (int j = 0; j < NJ; ++j) {
            cursor[j] = off;               // scatter base (padded offset)
            tb[j] = t;
            int nt = (counts[j] + TILE - 1) / TILE;
            t += nt;
            off += nt * TILE;
        }
        tb[NJ] = t;
        ntiles[0] = t;
    }
    __syncthreads();
    int ntot = tb[NJ];
    for (int tt = threadIdx.x; tt < ntot; tt += blockDim.x) {
        int j = 0;
        while (tb[j + 1] <= tt) ++j;
        tileExpert[tt] = j;
    }
}

// ---------------------------------------------------------------------------
// Kernel 3: scatter sample indices (perm pre-memset to -1; padded slots stay -1)
// ---------------------------------------------------------------------------
__global__ void k_scatter(const int* __restrict__ ids, int* __restrict__ cursor,
                          int* __restrict__ perm)
{
    __shared__ int lh[NJ], lbase[NJ];
    const int b = blockIdx.x * blockDim.x + threadIdx.x;
    if (threadIdx.x < NJ) lh[threadIdx.x] = 0;
    __syncthreads();
    int id = 0, rank = 0;
    if (b < B_N) { id = ids[b]; rank = atomicAdd(&lh[id], 1); }
    __syncthreads();
    if (threadIdx.x < NJ)
        lbase[threadIdx.x] = lh[threadIdx.x] ? atomicAdd(&cursor[threadIdx.x], lh[threadIdx.x]) : 0;
    __syncthreads();
    if (b < B_N) perm[lbase[id] + rank] = b;
}

// ---------------------------------------------------------------------------
// Kernel 4: fused MLP. Block = 32 samples (one expert), 4 waves; each wave
// owns a 64-row slice of the N-dim per layer; barriers between layers.
// Occupancy-first: LDS 21.6 KB, target VGPR<=128 -> 16+ waves/CU.
// MFMA 16x16x32 bf16 layouts (verified r1/r2):
//   A: lane holds A[lane&15][(lane>>4)*8+e]      (weights = A, rows)
//   B: lane holds B[(lane>>4)*8+e][lane&15]      (samples = B, cols)
//   D: col=lane&15 (sample), row=(lane>>4)*4+r   (output row)
// ---------------------------------------------------------------------------
__global__ __launch_bounds__(256, 4) void k_main(
    const float* __restrict__ x, float* __restrict__ out,
    const int* __restrict__ perm, const int* __restrict__ ntiles,
    const int* __restrict__ tileExpert,
    const unsigned short* __restrict__ w1c, const unsigned short* __restrict__ w2c,
    const unsigned short* __restrict__ vc,
    const float* __restrict__ bias1, const float* __restrict__ bias2,
    const float* __restrict__ biasv)
{
    __shared__ __align__(16) unsigned short s_z1[TILE][264];   // z1, then z2
    __shared__ __align__(16) union {
        unsigned short xb[TILE][72];   // bf16 input tile (dead after layer 1)
        float          lg[TILE][40];   // logits (born at heads)
    } s_u;
    __shared__ int s_rows[TILE];

    const int nt  = ntiles[0];
    const int bid = blockIdx.x;
    if (bid >= nt) return;

    // m204 bijective XCD swizzle: each XCD gets a contiguous chunk of
    // (expert-sorted) tile space -> expert weights live in 1-2 XCD L2s.
    const int q8 = nt >> 3, r8 = nt & 7;
    const int xcd = bid & 7, idx = bid >> 3;
    const int lbid = (xcd < r8 ? xcd * (q8 + 1) : r8 * (q8 + 1) + (xcd - r8) * q8) + idx;

    const int tid  = threadIdx.x;
    const int lane = tid & 63;
    const int wave = tid >> 6;
    const int l16  = lane & 15;
    const int lk   = lane >> 4;
    const int j    = tileExpert[lbid];

    if (tid < TILE) s_rows[tid] = perm[lbid * TILE + tid];
    for (int i = tid; i < TILE * 36; i += 256) ((unsigned int*)s_u.xb)[i] = 0u;
    __syncthreads();

    for (int i = tid; i < TILE * D_IN; i += 256) {
        int s = i / D_IN, k = i - s * D_IN;
        int r = s_rows[s];
        s_u.xb[s][k] = f2bf(r >= 0 ? x[(size_t)r * D_IN + k] : 0.f);
    }
    __syncthreads();

    const f32x4 vz = {0.f, 0.f, 0.f, 0.f};

    // ---- layer 1: z1[s][h] = relu(W1c[h]·xb[s] + b1[h]), wave owns 64 h ----
    {
        v8bf b1[2][2];
#pragma unroll
        for (int mt = 0; mt < 2; ++mt) {
            b1[mt][0] = *(const v8bf*)&s_u.xb[mt * 16 + l16][lk * 8];
            b1[mt][1] = *(const v8bf*)&s_u.xb[mt * 16 + l16][32 + lk * 8];
        }
        const unsigned short* w1p = w1c + ((size_t)j << 14) + (size_t)(wave * 64) * 64;
        f32x4 acc[4][2];
#pragma unroll
        for (int t = 0; t < 4; ++t) { acc[t][0] = vz; acc[t][1] = vz; }
#pragma unroll
        for (int t = 0; t < 4; ++t) {
            const unsigned short* rp = w1p + (t * 16 + l16) * 64;
            v8bf a0 = *(const v8bf*)&rp[lk * 8];
            v8bf a1 = *(const v8bf*)&rp[32 + lk * 8];
#pragma unroll
            for (int mt = 0; mt < 2; ++mt) {
                acc[t][mt] = __builtin_amdgcn_mfma_f32_16x16x32_bf16(a0, b1[mt][0], acc[t][mt], 0, 0, 0);
                acc[t][mt] = __builtin_amdgcn_mfma_f32_16x16x32_bf16(a1, b1[mt][1], acc[t][mt], 0, 0, 0);
            }
        }
#pragma unroll
        for (int t = 0; t < 4; ++t) {
            f32x4 bz = *(const f32x4*)&bias1[j * 256 + wave * 64 + t * 16 + lk * 4];
#pragma unroll
            for (int mt = 0; mt < 2; ++mt) {
                float v0 = acc[t][mt][0] + bz[0], v1 = acc[t][mt][1] + bz[1];
                float v2 = acc[t][mt][2] + bz[2], v3 = acc[t][mt][3] + bz[3];
                v0 = v0 > 0.f ? v0 : 0.f; v1 = v1 > 0.f ? v1 : 0.f;
                v2 = v2 > 0.f ? v2 : 0.f; v3 = v3 > 0.f ? v3 : 0.f;
                uint2 pk; pk.x = pack2(v0, v1); pk.y = pack2(v2, v3);
                *(uint2*)&s_z1[mt * 16 + l16][wave * 64 + t * 16 + lk * 4] = pk;
            }
        }
    }
    __syncthreads();

    // ---- layer 2: z2 = relu(z1 @ W2c^T + b2), wave owns 64 g-rows ----
    {
        f32x4 acc[4][2];
#pragma unroll
        for (int gt = 0; gt < 4; ++gt) { acc[gt][0] = vz; acc[gt][1] = vz; }
        const unsigned short* w2p = w2c + ((size_t)j << 16) + (size_t)(wave * 64) * 256;
#pragma unroll 2
        for (int hc = 0; hc < 8; ++hc) {
            v8bf bb0 = *(const v8bf*)&s_z1[l16][hc * 32 + lk * 8];
            v8bf bb1 = *(const v8bf*)&s_z1[16 + l16][hc * 32 + lk * 8];
#pragma unroll
            for (int gt = 0; gt < 4; ++gt) {
                v8bf a = *(const v8bf*)&w2p[(gt * 16 + l16) * 256 + hc * 32 + lk * 8];
                acc[gt][0] = __builtin_amdgcn_mfma_f32_16x16x32_bf16(a, bb0, acc[gt][0], 0, 0, 0);
                acc[gt][1] = __builtin_amdgcn_mfma_f32_16x16x32_bf16(a, bb1, acc[gt][1], 0, 0, 0);
            }
        }
        __syncthreads();   // all waves done READING z1 -> safe to overwrite
#pragma unroll
        for (int gt = 0; gt < 4; ++gt) {
            f32x4 bz = *(const f32x4*)&bias2[j * 256 + wave * 64 + gt * 16 + lk * 4];
#pragma unroll
            for (int mt = 0; mt < 2; ++mt) {
                float v0 = acc[gt][mt][0] + bz[0], v1 = acc[gt][mt][1] + bz[1];
                float v2 = acc[gt][mt][2] + bz[2], v3 = acc[gt][mt][3] + bz[3];
                v0 = v0 > 0.f ? v0 : 0.f; v1 = v1 > 0.f ? v1 : 0.f;
                v2 = v2 > 0.f ? v2 : 0.f; v3 = v3 > 0.f ? v3 : 0.f;
                uint2 pk; pk.x = pack2(v0, v1); pk.y = pack2(v2, v3);
                *(uint2*)&s_z1[mt * 16 + l16][wave * 64 + gt * 16 + lk * 4] = pk;
            }
        }
    }
    __syncthreads();

    // ---- heads: logits[s][qo] = Vc[qo]·z2[s] + bv[qo]; waves 0..2 ----
    if (wave < 3) {
        const unsigned short* vp = vc + (size_t)j * 12288 + (size_t)(wave * 16) * 256;
        f32x4 av[2] = {vz, vz};
#pragma unroll 2
        for (int gc = 0; gc < 8; ++gc) {
            v8bf bb0 = *(const v8bf*)&s_z1[l16][gc * 32 + lk * 8];
            v8bf bb1 = *(const v8bf*)&s_z1[16 + l16][gc * 32 + lk * 8];
            v8bf a = *(const v8bf*)&vp[l16 * 256 + gc * 32 + lk * 8];
            av[0] = __builtin_amdgcn_mfma_f32_16x16x32_bf16(a, bb0, av[0], 0, 0, 0);
            av[1] = __builtin_amdgcn_mfma_f32_16x16x32_bf16(a, bb1, av[1], 0, 0, 0);
        }
        int qb = wave * 16 + lk * 4;
        if (qb < 36) {   // rows >= 35 never read by softmax
            f32x4 bz = *(const f32x4*)&biasv[j * 48 + qb];
#pragma unroll
            for (int mt = 0; mt < 2; ++mt) {
                f32x4 v = av[mt] + bz;
                *(f32x4*)&s_u.lg[mt * 16 + l16][qb] = v;
            }
        }
    }
    __syncthreads();

    // ---- softmax over O=5 per (s,q), write out ----
    if (tid < TILE * NQ) {
        int s = tid / NQ, qq = tid - s * NQ;
        int r = s_rows[s];
        if (r >= 0) {
            float l[NO], mx = -1e30f;
#pragma unroll
            for (int o = 0; o < NO; ++o) {
                l[o] = s_u.lg[s][qq * NO + o];
                mx = l[o] > mx ? l[o] : mx;
            }
            float sum = 0.f, e[NO];
#pragma unroll
            for (int o = 0; o < NO; ++o) { e[o] = __expf(l[o] - mx); sum += e[o]; }
            float inv = 1.f / sum;
            float* op = out + (size_t)r * QO + qq * NO;
#pragma unroll
            for (int o = 0; o < NO; ++o) op[o] = e[o] * inv;
        }
    }
}

// ---------------------------------------------------------------------------
extern "C" void kernel_launch(void* const* d_in, const int* in_sizes, int n_in,
                              void* d_out, int out_size, void* d_ws, size_t ws_size,
                              hipStream_t stream)
{
    const float* x     = (const float*)d_in[0];
    const int*   ids   = (const int*)d_in[1];
    const float* W1_w  = (const float*)d_in[2];
    const float* W1_b  = (const float*)d_in[3];
    const float* W2_w  = (const float*)d_in[4];
    const float* W2_b  = (const float*)d_in[5];
    const float* W1a_w = (const float*)d_in[6];
    const float* W1a_b = (const float*)d_in[7];
    const float* W2a_w = (const float*)d_in[8];
    const float* W2a_b = (const float*)d_in[9];
    const float* V_w   = (const float*)d_in[10];
    const float* V_b   = (const float*)d_in[11];
    const float* Va_w  = (const float*)d_in[12];
    const float* Va_b  = (const float*)d_in[13];
    float* out = (float*)d_out;

    char* ws = (char*)d_ws;
    size_t off = 0;
    auto take = [&](size_t nbytes) -> void* {
        void* p = ws + off;
        off = (off + nbytes + 255) & ~(size_t)255;
        return p;
    };
    unsigned short* w1c = (unsigned short*)take((size_t)NJ * 256 * 64 * 2);
    unsigned short* w2c = (unsigned short*)take((size_t)NJ * 256 * 256 * 2);
    unsigned short* vc  = (unsigned short*)take((size_t)NJ * 48 * 256 * 2);
    float* bias1        = (float*)take((size_t)NJ * 256 * 4);
    float* bias2        = (float*)take((size_t)NJ * 256 * 4);
    float* biasv        = (float*)take((size_t)NJ * 48 * 4);
    int* counts         = (int*)take(NJ * 4);
    int* cursor         = (int*)take(NJ * 4);
    int* ntiles         = (int*)take(4);
    int* tileExpert     = (int*)take(MAXT * 4);
    int* perm           = (int*)take((size_t)MAXSLOTS * 4);

    hipMemsetAsync(counts, 0, NJ * sizeof(int), stream);
    hipMemsetAsync(perm, 0xFF, (size_t)MAXSLOTS * sizeof(int), stream);   // -1

    k_prep<<<768, 256, 0, stream>>>(ids, W1_w, W1_b, W2_w, W2_b, W1a_w, W1a_b,
                                    W2a_w, W2a_b, V_w, V_b, Va_w, Va_b,
                                    w1c, w2c, vc, bias1, bias2, biasv, counts);
    k_scan<<<1, 256, 0, stream>>>(counts, cursor, ntiles, tileExpert);
    k_scatter<<<(B_N + 255) / 256, 256, 0, stream>>>(ids, cursor, perm);
    k_main<<<MAXT, 256, 0, stream>>>(x, out, perm, ntiles, tileExpert,
                                     w1c, w2c, vc, bias1, bias2, biasv);
}

// Round 4
// 51.494 us; speedup vs baseline: 2.1934x; 1.0763x over previous
//
#include <hip/hip_runtime.h>
#include <stdint.h>

// Problem constants
#define B_N   32768
#define D_IN  35
#define NJ    12
#define NQ    7
#define NO    5
#define QO    35
#define TILE  32                       // samples per block
#define MAXSLOTS (B_N + NJ*TILE)       // 33152 padded permutation slots
#define MAXT     (MAXSLOTS/TILE)       // 1036 tiles max

typedef __bf16  v8bf  __attribute__((ext_vector_type(8)));
typedef float   f32x4 __attribute__((ext_vector_type(4)));

__device__ __forceinline__ unsigned short f2bf(float f) {
    unsigned int u = __builtin_bit_cast(unsigned int, f);
    u += 0x7FFFu + ((u >> 16) & 1u);   // round-to-nearest-even
    return (unsigned short)(u >> 16);
}
__device__ __forceinline__ unsigned int pack2(float a, float b) {
    return (unsigned int)f2bf(a) | ((unsigned int)f2bf(b) << 16);
}

// ---------------------------------------------------------------------------
// Kernel 1: combine shared+expert weights into bf16 (ones-col folded into f32
// biases). Block 0 additionally: histogram of ids (int4 loads, LDS atomics),
// padded prefix scan, tile table, and -1 fill of perm pad slots.
// No memsets needed anywhere; all ws state regenerated every call.
// w1c: [12][256][64] (k>=35 zero)   w2c: [12][256][256]   vc: [12][48][256]
// ---------------------------------------------------------------------------
__global__ void k_prep(const int* __restrict__ ids,
                       const float* __restrict__ W1_w, const float* __restrict__ W1_b,
                       const float* __restrict__ W2_w, const float* __restrict__ W2_b,
                       const float* __restrict__ W1a_w, const float* __restrict__ W1a_b,
                       const float* __restrict__ W2a_w, const float* __restrict__ W2a_b,
                       const float* __restrict__ V_w,  const float* __restrict__ V_b,
                       const float* __restrict__ Va_w, const float* __restrict__ Va_b,
                       unsigned short* __restrict__ w1c, unsigned short* __restrict__ w2c,
                       unsigned short* __restrict__ vc,
                       float* __restrict__ bias1, float* __restrict__ bias2,
                       float* __restrict__ biasv,
                       int* __restrict__ cursor, int* __restrict__ ntiles,
                       int* __restrict__ tileExpert, int* __restrict__ perm)
{
    const int tid = blockIdx.x * blockDim.x + threadIdx.x;
    const int nth = gridDim.x * blockDim.x;

    // w2c: 12*256*64 quads
    for (int q = tid; q < NJ * 256 * 64; q += nth) {
        int k4 = (q & 63) << 2, h = (q >> 6) & 255, jj = q >> 14;
        const float* a = &W2_w[h * 257 + k4];
        const float* b = &W2a_w[(jj * 256 + h) * 257 + k4];
        ushort4 o;
        o.x = f2bf(a[0] + b[0]); o.y = f2bf(a[1] + b[1]);
        o.z = f2bf(a[2] + b[2]); o.w = f2bf(a[3] + b[3]);
        *(ushort4*)&w2c[(size_t)q << 2] = o;
    }
    // w1c: 12*256*16 quads (k padded to 64)
    for (int q = tid; q < NJ * 256 * 16; q += nth) {
        int k4 = (q & 15) << 2, h = (q >> 4) & 255, jj = q >> 12;
        ushort4 o;
        float v[4];
#pragma unroll
        for (int e = 0; e < 4; ++e) {
            int k = k4 + e;
            v[e] = (k < D_IN) ? (W1_w[h * 36 + k] + W1a_w[(jj * 256 + h) * 36 + k]) : 0.f;
        }
        o.x = f2bf(v[0]); o.y = f2bf(v[1]); o.z = f2bf(v[2]); o.w = f2bf(v[3]);
        *(ushort4*)&w1c[(size_t)q << 2] = o;
    }
    // vc: 12*48*64 quads
    for (int q = tid; q < NJ * 48 * 64; q += nth) {
        int k4 = (q & 63) << 2, qo = (q >> 6) % 48, jj = q / (48 * 64);
        ushort4 o;
        if (qo < QO) {
            const float* a = &V_w[qo * 257 + k4];
            const float* b = &Va_w[(jj * QO + qo) * 257 + k4];
            o.x = f2bf(a[0] + b[0]); o.y = f2bf(a[1] + b[1]);
            o.z = f2bf(a[2] + b[2]); o.w = f2bf(a[3] + b[3]);
        } else {
            o.x = o.y = o.z = o.w = 0;
        }
        *(ushort4*)&vc[(size_t)q << 2] = o;
    }
    // biases (fold ones-column)
    for (int i = tid; i < NJ * 256; i += nth) {
        int h = i & 255, jj = i >> 8;
        bias1[i] = W1_w[h * 36 + 35] + W1a_w[(jj * 256 + h) * 36 + 35] + W1_b[h] + W1a_b[i];
        bias2[i] = W2_w[h * 257 + 256] + W2a_w[(jj * 256 + h) * 257 + 256] + W2_b[h] + W2a_b[i];
    }
    for (int i = tid; i < NJ * 48; i += nth) {
        int qo = i % 48, jj = i / 48;
        float v = 0.f;
        if (qo < QO) v = V_w[qo * 257 + 256] + Va_w[(jj * QO + qo) * 257 + 256]
                       + V_b[qo] + Va_b[jj * QO + qo];
        biasv[i] = v;
    }

    // ---- block 0 only: histogram + padded scan + tile table + pad fill ----
    if (blockIdx.x == 0) {
        __shared__ int lh[NJ];
        __shared__ int s_cur[NJ], s_cnt[NJ], s_nt[NJ], tb[NJ + 1];
        const int lt = threadIdx.x;
        if (lt < NJ) lh[lt] = 0;
        __syncthreads();
        const int4* ids4 = (const int4*)ids;
        for (int i = lt; i < B_N / 4; i += 256) {
            int4 v = ids4[i];
            atomicAdd(&lh[v.x], 1); atomicAdd(&lh[v.y], 1);
            atomicAdd(&lh[v.z], 1); atomicAdd(&lh[v.w], 1);
        }
        __syncthreads();
        if (lt == 0) {
            int off = 0, t = 0;
            for (int j = 0; j < NJ; ++j) {
                int c = lh[j];
                int nt = (c + TILE - 1) / TILE;
                cursor[j] = off;
                s_cur[j] = off; s_cnt[j] = c; s_nt[j] = nt; tb[j] = t;
                t += nt;
                off += nt * TILE;
            }
            tb[NJ] = t;
            ntiles[0] = t;
        }
        __syncthreads();
        const int ntot = tb[NJ];
        for (int tt = lt; tt < ntot; tt += 256) {
            int j = 0;
            while (tb[j + 1] <= tt) ++j;
            tileExpert[tt] = j;
        }
        // pad-slot fill (<=31 per expert)
        for (int p = lt; p < NJ * TILE; p += 256) {
            int j = p >> 5, o = p & 31;
            int c = s_cnt[j];
            int padN = s_nt[j] * TILE - c;
            if (o < padN) perm[s_cur[j] + c + o] = -1;
        }
    }
}

// ---------------------------------------------------------------------------
// Kernel 2: scatter sample indices into expert-sorted slots (order-free).
// ---------------------------------------------------------------------------
__global__ void k_scatter(const int* __restrict__ ids, int* __restrict__ cursor,
                          int* __restrict__ perm)
{
    __shared__ int lh[NJ], lbase[NJ];
    const int b = blockIdx.x * blockDim.x + threadIdx.x;
    if (threadIdx.x < NJ) lh[threadIdx.x] = 0;
    __syncthreads();
    int id = 0, rank = 0;
    if (b < B_N) { id = ids[b]; rank = atomicAdd(&lh[id], 1); }
    __syncthreads();
    if (threadIdx.x < NJ)
        lbase[threadIdx.x] = lh[threadIdx.x] ? atomicAdd(&cursor[threadIdx.x], lh[threadIdx.x]) : 0;
    __syncthreads();
    if (b < B_N) perm[lbase[id] + rank] = b;
}

// ---------------------------------------------------------------------------
// Kernel 3: fused MLP. Block = 32 samples (one expert), 4 waves; each wave
// owns a 64-row slice of the N-dim per layer; barriers between layers.
// Weight fragments are REGISTER-PREFETCHED across each barrier (loads are
// independent of LDS contents; compiler can't hoist across s_barrier itself).
// MFMA 16x16x32 bf16 layouts:
//   A: lane holds A[lane&15][(lane>>4)*8+e]      (weights = A, rows)
//   B: lane holds B[(lane>>4)*8+e][lane&15]      (samples = B, cols)
//   D: col=lane&15 (sample), row=(lane>>4)*4+r   (output row)
// ---------------------------------------------------------------------------
__global__ __launch_bounds__(256, 4) void k_main(
    const float* __restrict__ x, float* __restrict__ out,
    const int* __restrict__ perm, const int* __restrict__ ntiles,
    const int* __restrict__ tileExpert,
    const unsigned short* __restrict__ w1c, const unsigned short* __restrict__ w2c,
    const unsigned short* __restrict__ vc,
    const float* __restrict__ bias1, const float* __restrict__ bias2,
    const float* __restrict__ biasv)
{
    __shared__ __align__(16) unsigned short s_z1[TILE][264];   // z1, then z2
    __shared__ __align__(16) union {
        unsigned short xb[TILE][72];   // bf16 input tile (dead after layer 1)
        float          lg[TILE][40];   // logits (born at heads)
    } s_u;
    __shared__ int s_rows[TILE];

    const int nt  = ntiles[0];
    const int bid = blockIdx.x;
    if (bid >= nt) return;

    // m204 bijective XCD swizzle: contiguous (expert-sorted) chunk per XCD.
    const int q8 = nt >> 3, r8 = nt & 7;
    const int xcd = bid & 7, idx = bid >> 3;
    const int lbid = (xcd < r8 ? xcd * (q8 + 1) : r8 * (q8 + 1) + (xcd - r8) * q8) + idx;

    const int tid  = threadIdx.x;
    const int lane = tid & 63;
    const int wave = tid >> 6;
    const int l16  = lane & 15;
    const int lk   = lane >> 4;
    const int j    = tileExpert[lbid];

    // ---- prefetch ALL of this wave's layer-1 A fragments (32 VGPR) ----
    const unsigned short* w1p = w1c + ((size_t)j << 14) + (size_t)(wave * 64) * 64;
    v8bf w1a0[4], w1a1[4];
#pragma unroll
    for (int t = 0; t < 4; ++t) {
        const unsigned short* rp = w1p + (t * 16 + l16) * 64;
        w1a0[t] = *(const v8bf*)&rp[lk * 8];
        w1a1[t] = *(const v8bf*)&rp[32 + lk * 8];
    }

    if (tid < TILE) s_rows[tid] = perm[lbid * TILE + tid];
    for (int i = tid; i < TILE * 36; i += 256) ((unsigned int*)s_u.xb)[i] = 0u;
    __syncthreads();

    for (int i = tid; i < TILE * D_IN; i += 256) {
        int s = i / D_IN, k = i - s * D_IN;
        int r = s_rows[s];
        s_u.xb[s][k] = f2bf(r >= 0 ? x[(size_t)r * D_IN + k] : 0.f);
    }
    __syncthreads();

    const f32x4 vz = {0.f, 0.f, 0.f, 0.f};

    // ---- layer 1: z1[s][h] = relu(W1c[h]·xb[s] + b1[h]), wave owns 64 h ----
    {
        v8bf b1[2][2];
#pragma unroll
        for (int mt = 0; mt < 2; ++mt) {
            b1[mt][0] = *(const v8bf*)&s_u.xb[mt * 16 + l16][lk * 8];
            b1[mt][1] = *(const v8bf*)&s_u.xb[mt * 16 + l16][32 + lk * 8];
        }
        f32x4 acc[4][2];
#pragma unroll
        for (int t = 0; t < 4; ++t) { acc[t][0] = vz; acc[t][1] = vz; }
#pragma unroll
        for (int t = 0; t < 4; ++t) {
#pragma unroll
            for (int mt = 0; mt < 2; ++mt) {
                acc[t][mt] = __builtin_amdgcn_mfma_f32_16x16x32_bf16(w1a0[t], b1[mt][0], acc[t][mt], 0, 0, 0);
                acc[t][mt] = __builtin_amdgcn_mfma_f32_16x16x32_bf16(w1a1[t], b1[mt][1], acc[t][mt], 0, 0, 0);
            }
        }
        // prefetch layer-2 hc=0 A fragments before the barrier (16 VGPR)
        const unsigned short* w2p = w2c + ((size_t)j << 16) + (size_t)(wave * 64) * 256;
        v8bf a2pre[4];
#pragma unroll
        for (int gt = 0; gt < 4; ++gt)
            a2pre[gt] = *(const v8bf*)&w2p[(gt * 16 + l16) * 256 + lk * 8];

#pragma unroll
        for (int t = 0; t < 4; ++t) {
            f32x4 bz = *(const f32x4*)&bias1[j * 256 + wave * 64 + t * 16 + lk * 4];
#pragma unroll
            for (int mt = 0; mt < 2; ++mt) {
                float v0 = acc[t][mt][0] + bz[0], v1 = acc[t][mt][1] + bz[1];
                float v2 = acc[t][mt][2] + bz[2], v3 = acc[t][mt][3] + bz[3];
                v0 = v0 > 0.f ? v0 : 0.f; v1 = v1 > 0.f ? v1 : 0.f;
                v2 = v2 > 0.f ? v2 : 0.f; v3 = v3 > 0.f ? v3 : 0.f;
                uint2 pk; pk.x = pack2(v0, v1); pk.y = pack2(v2, v3);
                *(uint2*)&s_z1[mt * 16 + l16][wave * 64 + t * 16 + lk * 4] = pk;
            }
        }
        __syncthreads();

        // ---- layer 2: z2 = relu(z1 @ W2c^T + b2), wave owns 64 g-rows ----
        f32x4 acc2[4][2];
#pragma unroll
        for (int gt = 0; gt < 4; ++gt) { acc2[gt][0] = vz; acc2[gt][1] = vz; }
        {   // hc = 0 (prefetched A)
            v8bf bb0 = *(const v8bf*)&s_z1[l16][lk * 8];
            v8bf bb1 = *(const v8bf*)&s_z1[16 + l16][lk * 8];
#pragma unroll
            for (int gt = 0; gt < 4; ++gt) {
                acc2[gt][0] = __builtin_amdgcn_mfma_f32_16x16x32_bf16(a2pre[gt], bb0, acc2[gt][0], 0, 0, 0);
                acc2[gt][1] = __builtin_amdgcn_mfma_f32_16x16x32_bf16(a2pre[gt], bb1, acc2[gt][1], 0, 0, 0);
            }
        }
#pragma unroll 2
        for (int hc = 1; hc < 8; ++hc) {
            v8bf bb0 = *(const v8bf*)&s_z1[l16][hc * 32 + lk * 8];
            v8bf bb1 = *(const v8bf*)&s_z1[16 + l16][hc * 32 + lk * 8];
#pragma unroll
            for (int gt = 0; gt < 4; ++gt) {
                v8bf a = *(const v8bf*)&w2p[(gt * 16 + l16) * 256 + hc * 32 + lk * 8];
                acc2[gt][0] = __builtin_amdgcn_mfma_f32_16x16x32_bf16(a, bb0, acc2[gt][0], 0, 0, 0);
                acc2[gt][1] = __builtin_amdgcn_mfma_f32_16x16x32_bf16(a, bb1, acc2[gt][1], 0, 0, 0);
            }
        }
        // prefetch heads gc=0 A fragment before the barrier
        const unsigned short* vp = vc + (size_t)j * 12288 + (size_t)(wave * 16) * 256;
        v8bf a3pre;
        if (wave < 3) a3pre = *(const v8bf*)&vp[l16 * 256 + lk * 8];

        __syncthreads();   // all waves done READING z1 -> safe to overwrite
#pragma unroll
        for (int gt = 0; gt < 4; ++gt) {
            f32x4 bz = *(const f32x4*)&bias2[j * 256 + wave * 64 + gt * 16 + lk * 4];
#pragma unroll
            for (int mt = 0; mt < 2; ++mt) {
                float v0 = acc2[gt][mt][0] + bz[0], v1 = acc2[gt][mt][1] + bz[1];
                float v2 = acc2[gt][mt][2] + bz[2], v3 = acc2[gt][mt][3] + bz[3];
                v0 = v0 > 0.f ? v0 : 0.f; v1 = v1 > 0.f ? v1 : 0.f;
                v2 = v2 > 0.f ? v2 : 0.f; v3 = v3 > 0.f ? v3 : 0.f;
                uint2 pk; pk.x = pack2(v0, v1); pk.y = pack2(v2, v3);
                *(uint2*)&s_z1[mt * 16 + l16][wave * 64 + gt * 16 + lk * 4] = pk;
            }
        }
        __syncthreads();

        // ---- heads: logits[s][qo] = Vc[qo]·z2[s] + bv[qo]; waves 0..2 ----
        if (wave < 3) {
            f32x4 av[2] = {vz, vz};
            {   // gc = 0 (prefetched A)
                v8bf bb0 = *(const v8bf*)&s_z1[l16][lk * 8];
                v8bf bb1 = *(const v8bf*)&s_z1[16 + l16][lk * 8];
                av[0] = __builtin_amdgcn_mfma_f32_16x16x32_bf16(a3pre, bb0, av[0], 0, 0, 0);
                av[1] = __builtin_amdgcn_mfma_f32_16x16x32_bf16(a3pre, bb1, av[1], 0, 0, 0);
            }
#pragma unroll 4
            for (int gc = 1; gc < 8; ++gc) {
                v8bf bb0 = *(const v8bf*)&s_z1[l16][gc * 32 + lk * 8];
                v8bf bb1 = *(const v8bf*)&s_z1[16 + l16][gc * 32 + lk * 8];
                v8bf a = *(const v8bf*)&vp[l16 * 256 + gc * 32 + lk * 8];
                av[0] = __builtin_amdgcn_mfma_f32_16x16x32_bf16(a, bb0, av[0], 0, 0, 0);
                av[1] = __builtin_amdgcn_mfma_f32_16x16x32_bf16(a, bb1, av[1], 0, 0, 0);
            }
            int qb = wave * 16 + lk * 4;
            if (qb < 36) {   // rows >= 35 never read by softmax
                f32x4 bz = *(const f32x4*)&biasv[j * 48 + qb];
#pragma unroll
                for (int mt = 0; mt < 2; ++mt) {
                    f32x4 v = av[mt] + bz;
                    *(f32x4*)&s_u.lg[mt * 16 + l16][qb] = v;
                }
            }
        }
    }
    __syncthreads();

    // ---- softmax over O=5 per (s,q), write out ----
    if (tid < TILE * NQ) {
        int s = tid / NQ, qq = tid - s * NQ;
        int r = s_rows[s];
        if (r >= 0) {
            float l[NO], mx = -1e30f;
#pragma unroll
            for (int o = 0; o < NO; ++o) {
                l[o] = s_u.lg[s][qq * NO + o];
                mx = l[o] > mx ? l[o] : mx;
            }
            float sum = 0.f, e[NO];
#pragma unroll
            for (int o = 0; o < NO; ++o) { e[o] = __expf(l[o] - mx); sum += e[o]; }
            float inv = 1.f / sum;
            float* op = out + (size_t)r * QO + qq * NO;
#pragma unroll
            for (int o = 0; o < NO; ++o) op[o] = e[o] * inv;
        }
    }
}

// ---------------------------------------------------------------------------
extern "C" void kernel_launch(void* const* d_in, const int* in_sizes, int n_in,
                              void* d_out, int out_size, void* d_ws, size_t ws_size,
                              hipStream_t stream)
{
    const float* x     = (const float*)d_in[0];
    const int*   ids   = (const int*)d_in[1];
    const float* W1_w  = (const float*)d_in[2];
    const float* W1_b  = (const float*)d_in[3];
    const float* W2_w  = (const float*)d_in[4];
    const float* W2_b  = (const float*)d_in[5];
    const float* W1a_w = (const float*)d_in[6];
    const float* W1a_b = (const float*)d_in[7];
    const float* W2a_w = (const float*)d_in[8];
    const float* W2a_b = (const float*)d_in[9];
    const float* V_w   = (const float*)d_in[10];
    const float* V_b   = (const float*)d_in[11];
    const float* Va_w  = (const float*)d_in[12];
    const float* Va_b  = (const float*)d_in[13];
    float* out = (float*)d_out;

    char* ws = (char*)d_ws;
    size_t off = 0;
    auto take = [&](size_t nbytes) -> void* {
        void* p = ws + off;
        off = (off + nbytes + 255) & ~(size_t)255;
        return p;
    };
    unsigned short* w1c = (unsigned short*)take((size_t)NJ * 256 * 64 * 2);
    unsigned short* w2c = (unsigned short*)take((size_t)NJ * 256 * 256 * 2);
    unsigned short* vc  = (unsigned short*)take((size_t)NJ * 48 * 256 * 2);
    float* bias1        = (float*)take((size_t)NJ * 256 * 4);
    float* bias2        = (float*)take((size_t)NJ * 256 * 4);
    float* biasv        = (float*)take((size_t)NJ * 48 * 4);
    int* cursor         = (int*)take(NJ * 4);
    int* ntiles         = (int*)take(4);
    int* tileExpert     = (int*)take(MAXT * 4);
    int* perm           = (int*)take((size_t)MAXSLOTS * 4);

    k_prep<<<768, 256, 0, stream>>>(ids, W1_w, W1_b, W2_w, W2_b, W1a_w, W1a_b,
                                    W2a_w, W2a_b, V_w, V_b, Va_w, Va_b,
                                    w1c, w2c, vc, bias1, bias2, biasv,
                                    cursor, ntiles, tileExpert, perm);
    k_scatter<<<(B_N + 255) / 256, 256, 0, stream>>>(ids, cursor, perm);
    k_main<<<MAXT, 256, 0, stream>>>(x, out, perm, ntiles, tileExpert,
                                     w1c, w2c, vc, bias1, bias2, biasv);
}